// Round 1
// baseline (540.832 us; speedup 1.0000x reference)
//
#include <hip/hip_runtime.h>

// SdfParseLoss: scatter-min/max of sdf over pixel grid, then masked mean loss.
// H=256, W=192, B=64, V=100000. Output: 64 floats.

#define HH 256
#define WW 192
#define HW (HH * WW)
#define NB 64
#define NV 100000
#define BIG 9999.0f

// Order-preserving float <-> uint transform so unsigned atomicMin/Max give
// float min/max (handles negatives correctly).
__device__ __forceinline__ unsigned fkey(float f) {
    unsigned u = __float_as_uint(f);
    return (u & 0x80000000u) ? ~u : (u | 0x80000000u);
}
__device__ __forceinline__ float funkey(unsigned k) {
    unsigned u = (k & 0x80000000u) ? (k ^ 0x80000000u) : ~k;
    return __uint_as_float(u);
}

// key(+inf) = 0xFF800000 ; key(-inf) = 0x007FFFFF
#define KEY_POS_INF 0xFF800000u
#define KEY_NEG_INF 0x007FFFFFu

__global__ void init_kernel(uint4* __restrict__ minK, uint4* __restrict__ maxK, int n4) {
    int i = blockIdx.x * blockDim.x + threadIdx.x;
    if (i < n4) {
        minK[i] = make_uint4(KEY_POS_INF, KEY_POS_INF, KEY_POS_INF, KEY_POS_INF);
        maxK[i] = make_uint4(KEY_NEG_INF, KEY_NEG_INF, KEY_NEG_INF, KEY_NEG_INF);
    }
}

__global__ void scatter_kernel(const float* __restrict__ sdf,
                               const float2* __restrict__ mesh,
                               unsigned* __restrict__ minK,
                               unsigned* __restrict__ maxK) {
    int v = blockIdx.x * blockDim.x + threadIdx.x;
    int b = blockIdx.y;
    if (v >= NV) return;
    size_t i = (size_t)b * NV + v;
    float2 xy = mesh[i];
    int x = (int)xy.x;  // trunc toward zero, matches jnp astype(int32)
    int y = (int)xy.y;
    // invalid vertices contribute INF to min / -INF to max at pixel 0 in the
    // reference -> neutral vs our +/-inf init (both land in the "empty"
    // branch of the epilogue). Skip them.
    if ((unsigned)x >= WW || (unsigned)y >= HH) return;
    unsigned k = fkey(sdf[i]);
    int p = b * HW + y * WW + x;
    atomicMin(&minK[p], k);
    atomicMax(&maxK[p], k);
}

__global__ void reduce_kernel(const unsigned* __restrict__ minK,
                              const unsigned* __restrict__ maxK,
                              const int* __restrict__ gt,
                              const float* __restrict__ thr_p,
                              float* __restrict__ sums,
                              unsigned* __restrict__ counts) {
    const int CH = 8;            // blocks per batch
    int b = blockIdx.x / CH;
    int c = blockIdx.x % CH;
    float thr = thr_p[0];
    int base = b * HW + c * (HW / CH);
    float lsum = 0.f;
    int lpos = 0;
    for (int p = threadIdx.x; p < HW / CH; p += blockDim.x) {
        int idx = base + p;
        int g = gt[idx];
        float pmin = funkey(minK[idx]);
        float pmax = funkey(maxK[idx]);
        pmin = (pmin >= BIG) ? 0.f : pmin;        // empty/all-invalid -> 0
        pmax = (pmax <= -BIG) ? thr : pmax;       // empty/all-invalid -> thresh
        if (g == 1) { lsum += fabsf(pmin); lpos = 1; }
        else if (g == 0) { lsum += fabsf(pmax - thr); }
    }
    // wave (64-lane) reduction
    #pragma unroll
    for (int off = 32; off > 0; off >>= 1)
        lsum += __shfl_down(lsum, off, 64);
    unsigned long long m = __ballot(lpos != 0);
    int lane = threadIdx.x & 63;
    if (lane == 0) {
        atomicAdd(&sums[b], lsum);
        if (m) atomicOr(&counts[b], 1u);
    }
}

__global__ void final_kernel(const float* __restrict__ sums,
                             const unsigned* __restrict__ counts,
                             const float* __restrict__ pv,
                             float* __restrict__ out) {
    int b = threadIdx.x;
    if (b < NB) {
        float s = sums[b] * (1.0f / HW) * pv[b];
        out[b] = counts[b] ? s : 0.0f;
    }
}

extern "C" void kernel_launch(void* const* d_in, const int* in_sizes, int n_in,
                              void* d_out, int out_size, void* d_ws, size_t ws_size,
                              hipStream_t stream) {
    const float*  sdf  = (const float*)d_in[0];
    const float2* mesh = (const float2*)d_in[1];
    const int*    gt   = (const int*)d_in[2];
    const float*  thr  = (const float*)d_in[3];
    const float*  pv   = (const float*)d_in[5];   // parse_valid [B,1,1]
    float* out = (float*)d_out;

    char* ws = (char*)d_ws;
    unsigned* minK   = (unsigned*)ws;
    unsigned* maxK   = (unsigned*)(ws + (size_t)NB * HW * 4);
    float*    sums   = (float*)   (ws + (size_t)2 * NB * HW * 4);
    unsigned* counts = (unsigned*)(ws + (size_t)2 * NB * HW * 4 + NB * 4);

    // zero the per-batch accumulators (ws is poisoned 0xAA before every call)
    hipMemsetAsync(sums, 0, NB * 4 * 2, stream);

    int n4 = NB * HW / 4;
    init_kernel<<<(n4 + 255) / 256, 256, 0, stream>>>((uint4*)minK, (uint4*)maxK, n4);

    dim3 sg((NV + 255) / 256, NB);
    scatter_kernel<<<sg, 256, 0, stream>>>(sdf, mesh, minK, maxK);

    reduce_kernel<<<NB * 8, 256, 0, stream>>>(minK, maxK, gt, thr, sums, counts);

    final_kernel<<<1, 64, 0, stream>>>(sums, counts, pv, out);
}

// Round 2
// 327.700 us; speedup vs baseline: 1.6504x; 1.6504x over previous
//
#include <hip/hip_runtime.h>

// SdfParseLoss: scatter-min/max of sdf over pixel grid, then masked mean loss.
// H=256, W=192, B=64, V=100000. Output: 64 floats.
//
// Round 2: single-atomic scatter. Per-pixel only min (gt==1) or max (gt==0)
// is ever consumed, so store fkey(sdf) for pos pixels and ~fkey(sdf) for neg
// pixels in ONE array and use atomicMin for both. Empty pixels (key stays
// 0xFFFFFFFF) contribute exactly 0 to the loss in both branches
// (pos: |0|=0, neg: |thr-thr|=0), so the reduce just skips them.

#define HH 256
#define WW 192
#define HW (HH * WW)
#define NB 64
#define NV 100000
#define EMPTY_KEY 0xFFFFFFFFu

// Order-preserving float <-> uint transform so unsigned atomicMin gives
// float min (handles negatives correctly).
__device__ __forceinline__ unsigned fkey(float f) {
    unsigned u = __float_as_uint(f);
    return (u & 0x80000000u) ? ~u : (u | 0x80000000u);
}
__device__ __forceinline__ float funkey(unsigned k) {
    unsigned u = (k & 0x80000000u) ? (k ^ 0x80000000u) : ~k;
    return __uint_as_float(u);
}

__global__ void scatter_kernel(const float* __restrict__ sdf,
                               const float2* __restrict__ mesh,
                               const int* __restrict__ gt,
                               unsigned* __restrict__ keys) {
    int v = blockIdx.x * blockDim.x + threadIdx.x;
    int b = blockIdx.y;
    if (v >= NV) return;
    size_t i = (size_t)b * NV + v;
    float2 xy = mesh[i];
    int x = (int)xy.x;  // trunc toward zero, matches jnp astype(int32)
    int y = (int)xy.y;
    // invalid vertices are provably neutral (see round-1 analysis); skip.
    if ((unsigned)x >= WW || (unsigned)y >= HH) return;
    int p = b * HW + y * WW + x;
    unsigned k = fkey(sdf[i]);
    if (gt[p] == 0) k = ~k;       // neg pixel: min of ~key == max of key
    atomicMin(&keys[p], k);
}

__global__ void reduce_kernel(const uint4* __restrict__ keys,
                              const int4* __restrict__ gt,
                              const float* __restrict__ thr_p,
                              float* __restrict__ sums,
                              unsigned* __restrict__ counts) {
    const int CH = 8;               // blocks per batch
    int b = blockIdx.x / CH;
    int c = blockIdx.x % CH;
    float thr = thr_p[0];
    const int Q = HW / 4 / CH;      // uint4 per chunk = 1536
    int base = b * (HW / 4) + c * Q;
    float lsum = 0.f;
    int lpos = 0;
    for (int q = threadIdx.x; q < Q; q += blockDim.x) {
        uint4 kv = keys[base + q];
        int4  gv = gt[base + q];
        unsigned ka[4] = {kv.x, kv.y, kv.z, kv.w};
        int      ga[4] = {gv.x, gv.y, gv.z, gv.w};
        #pragma unroll
        for (int j = 0; j < 4; ++j) {
            unsigned k = ka[j];
            int g = ga[j];
            if (g == 1) lpos = 1;
            if (k != EMPTY_KEY) {
                lsum += (g == 1) ? fabsf(funkey(k)) : fabsf(funkey(~k) - thr);
            }
        }
    }
    // wave (64-lane) reduction
    #pragma unroll
    for (int off = 32; off > 0; off >>= 1)
        lsum += __shfl_down(lsum, off, 64);
    unsigned long long m = __ballot(lpos != 0);
    int lane = threadIdx.x & 63;
    if (lane == 0) {
        atomicAdd(&sums[b], lsum);
        if (m) atomicOr(&counts[b], 1u);
    }
}

__global__ void final_kernel(const float* __restrict__ sums,
                             const unsigned* __restrict__ counts,
                             const float* __restrict__ pv,
                             float* __restrict__ out) {
    int b = threadIdx.x;
    if (b < NB) {
        float s = sums[b] * (1.0f / HW) * pv[b];
        out[b] = counts[b] ? s : 0.0f;
    }
}

extern "C" void kernel_launch(void* const* d_in, const int* in_sizes, int n_in,
                              void* d_out, int out_size, void* d_ws, size_t ws_size,
                              hipStream_t stream) {
    const float*  sdf  = (const float*)d_in[0];
    const float2* mesh = (const float2*)d_in[1];
    const int*    gt   = (const int*)d_in[2];
    const float*  thr  = (const float*)d_in[3];
    const float*  pv   = (const float*)d_in[5];   // parse_valid [B,1,1]
    float* out = (float*)d_out;

    char* ws = (char*)d_ws;
    unsigned* keys   = (unsigned*)ws;
    float*    sums   = (float*)   (ws + (size_t)NB * HW * 4);
    unsigned* counts = (unsigned*)(ws + (size_t)NB * HW * 4 + NB * 4);

    // key init: 0xFF bytes == EMPTY_KEY everywhere (atomicMin identity)
    hipMemsetAsync(keys, 0xFF, (size_t)NB * HW * 4, stream);
    // per-batch accumulators (sums then counts, contiguous)
    hipMemsetAsync(sums, 0, NB * 4 * 2, stream);

    dim3 sg((NV + 255) / 256, NB);
    scatter_kernel<<<sg, 256, 0, stream>>>(sdf, mesh, gt, keys);

    reduce_kernel<<<NB * 8, 256, 0, stream>>>((const uint4*)keys, (const int4*)gt,
                                              thr, sums, counts);

    final_kernel<<<1, 64, 0, stream>>>(sums, counts, pv, out);
}

// Round 3
// 169.530 us; speedup vs baseline: 3.1902x; 1.9330x over previous
//
#include <hip/hip_runtime.h>

// SdfParseLoss: scatter-min/max of sdf over pixel grid, then masked mean loss.
// H=256, W=192, B=64, V=100000. Output: 64 floats.
//
// Round 3: fused LDS-binned scatter+reduce. Grid = B*4 blocks; block (b,q)
// owns pixel quarter q of batch b (12288 pixels, 48KB LDS keys + 12KB LDS gt
// bytes), streams ALL of batch b's vertices (coalesced float4), filters to
// its range, LDS-atomicMin (gt==0 pixels store ~key so min == max). Then it
// reduces its quarter's loss in-place and emits one atomicAdd per wave.
// No global keys array, no global atomics on pixels, no separate reduce pass.

#define HH 256
#define WW 192
#define HW (HH * WW)
#define NB 64
#define NV 100000
#define S 4
#define RANGE (HW / S)          // 12288 pixels per block
#define EMPTY_KEY 0xFFFFFFFFu

// Order-preserving float <-> uint transform so unsigned min gives float min.
__device__ __forceinline__ unsigned fkey(float f) {
    unsigned u = __float_as_uint(f);
    return (u & 0x80000000u) ? ~u : (u | 0x80000000u);
}
__device__ __forceinline__ float funkey(unsigned k) {
    unsigned u = (k & 0x80000000u) ? (k ^ 0x80000000u) : ~k;
    return __uint_as_float(u);
}

__global__ __launch_bounds__(1024) void fused_kernel(
        const float* __restrict__ sdf,
        const float* __restrict__ mesh,     // [B,V,2] interleaved
        const int* __restrict__ gt,
        const float* __restrict__ thr_p,
        float* __restrict__ sums,
        unsigned* __restrict__ counts) {
    __shared__ unsigned ldsk[RANGE];        // 48 KB
    __shared__ unsigned char gtb[RANGE];    // 12 KB
    const int b  = blockIdx.x >> 2;
    const int q  = blockIdx.x & 3;
    const int p0 = q * RANGE;
    const int tid = threadIdx.x;

    // init keys + stage gt quarter into LDS; track pos-pixel existence
    int lpos = 0;
    const int* gtbase = gt + b * HW + p0;
    for (int j = tid; j < RANGE; j += 1024) {
        ldsk[j] = EMPTY_KEY;
        int g = gtbase[j];
        gtb[j] = (unsigned char)g;
        lpos |= (g == 1);
    }
    __syncthreads();

    // stream the batch's vertices: 4 verts per thread-iteration
    const float4* sdf4 = (const float4*)(sdf + (size_t)b * NV);
    const float4* m4   = (const float4*)(mesh + (size_t)b * NV * 2);
    const float thr = thr_p[0];
    for (int g = tid; g < NV / 4; g += 1024) {
        float4 s4 = sdf4[g];
        float4 ma = m4[2 * g];
        float4 mb = m4[2 * g + 1];
        float xs[4] = {ma.x, ma.z, mb.x, mb.z};
        float ys[4] = {ma.y, ma.w, mb.y, mb.w};
        float ss[4] = {s4.x, s4.y, s4.z, s4.w};
        #pragma unroll
        for (int j = 0; j < 4; ++j) {
            int x = (int)xs[j];   // trunc toward zero == jnp astype(int32)
            int y = (int)ys[j];
            if ((unsigned)x < WW && (unsigned)y < HH) {
                int p = y * WW + x - p0;
                if ((unsigned)p < RANGE) {
                    unsigned k = fkey(ss[j]);
                    if (gtb[p] == 0) k = ~k;   // neg pixel: min of ~k == max
                    atomicMin(&ldsk[p], k);
                }
            }
        }
    }
    __syncthreads();

    // partial loss over this quarter (empty pixels contribute exactly 0)
    float lsum = 0.f;
    for (int j = tid; j < RANGE; j += 1024) {
        unsigned k = ldsk[j];
        if (k != EMPTY_KEY)
            lsum += gtb[j] ? fabsf(funkey(k)) : fabsf(funkey(~k) - thr);
    }
    #pragma unroll
    for (int off = 32; off > 0; off >>= 1)
        lsum += __shfl_down(lsum, off, 64);
    unsigned long long m = __ballot(lpos != 0);
    if ((tid & 63) == 0) {
        atomicAdd(&sums[b], lsum);
        if (m) atomicOr(&counts[b], 1u);
    }
}

__global__ void final_kernel(const float* __restrict__ sums,
                             const unsigned* __restrict__ counts,
                             const float* __restrict__ pv,
                             float* __restrict__ out) {
    int b = threadIdx.x;
    if (b < NB) {
        float s = sums[b] * (1.0f / HW) * pv[b];
        out[b] = counts[b] ? s : 0.0f;
    }
}

extern "C" void kernel_launch(void* const* d_in, const int* in_sizes, int n_in,
                              void* d_out, int out_size, void* d_ws, size_t ws_size,
                              hipStream_t stream) {
    const float* sdf  = (const float*)d_in[0];
    const float* mesh = (const float*)d_in[1];
    const int*   gt   = (const int*)d_in[2];
    const float* thr  = (const float*)d_in[3];
    const float* pv   = (const float*)d_in[5];   // parse_valid [B,1,1]
    float* out = (float*)d_out;

    float*    sums   = (float*)d_ws;
    unsigned* counts = (unsigned*)((char*)d_ws + NB * 4);

    // ws is poisoned 0xAA before every call: zero sums+counts (contiguous)
    hipMemsetAsync(sums, 0, NB * 4 * 2, stream);

    fused_kernel<<<NB * S, 1024, 0, stream>>>(sdf, mesh, gt, thr, sums, counts);

    final_kernel<<<1, 64, 0, stream>>>(sums, counts, pv, out);
}